// Round 11
// baseline (543.952 us; speedup 1.0000x reference)
//
#include <hip/hip_runtime.h>
#include <stdint.h>

#define NEGF (-1.0e8f)
#define NCELL (512 * 512)
#define INVLN2 1.4426950408889634f
#define NIV 39  // intervals of 32 diagonals; skew 32/wave

// raw barrier: LDS ordering only (never drains vmcnt -> global ops stay in flight)
#define BAR() asm volatile("s_waitcnt lgkmcnt(0)\n\ts_barrier" ::: "memory")

#define REP32(X) X(0) X(1) X(2) X(3) X(4) X(5) X(6) X(7) X(8) X(9) X(10) X(11) X(12) X(13) X(14) X(15) \
                 X(16) X(17) X(18) X(19) X(20) X(21) X(22) X(23) X(24) X(25) X(26) X(27) X(28) X(29) X(30) X(31)
#define REP33(X) REP32(X) X(32)
#define LIST1_32(X) X(1) X(2) X(3) X(4) X(5) X(6) X(7) X(8) X(9) X(10) X(11) X(12) X(13) X(14) X(15) X(16) \
                    X(17) X(18) X(19) X(20) X(21) X(22) X(23) X(24) X(25) X(26) X(27) X(28) X(29) X(30) X(31) X(32)

__device__ __forceinline__ float exp2f_(float x) {
#if __has_builtin(__builtin_amdgcn_exp2f)
  return __builtin_amdgcn_exp2f(x);
#else
  return exp2f(x);
#endif
}
__device__ __forceinline__ float log2f_(float x) {
#if __has_builtin(__builtin_amdgcn_logf)
  return __builtin_amdgcn_logf(x);
#else
  return log2f(x);
#endif
}
__device__ __forceinline__ uint32_t pknorm16(float a, float b) {
#if __has_builtin(__builtin_amdgcn_cvt_pknorm_u16)
  typedef unsigned short u2v __attribute__((ext_vector_type(2)));
  union { u2v v; uint32_t u; } cv;
  cv.v = __builtin_amdgcn_cvt_pknorm_u16(a, b);
  return cv.u;
#else
  uint32_t pa = (uint32_t)(a * 65535.0f + 0.5f);
  uint32_t pb = (uint32_t)(b * 65535.0f + 0.5f);
  return pa | (pb << 16);
#endif
}

// DPP wave shifts: 0x138 wave_shr:1 (lane l <- l-1, lane0 <- old), 0x130 wave_shl:1 (lane l <- l+1, lane63 <- old)
__device__ __forceinline__ float dpp_shr1_f(float src, float old0) {
  return __int_as_float(__builtin_amdgcn_update_dpp(
      __float_as_int(old0), __float_as_int(src), 0x138, 0xF, 0xF, false));
}
__device__ __forceinline__ float dpp_shl1_f(float src, float old63) {
  return __int_as_float(__builtin_amdgcn_update_dpp(
      __float_as_int(old63), __float_as_int(src), 0x130, 0xF, 0xF, false));
}
__device__ __forceinline__ uint32_t dpp_shl1_u(uint32_t src, uint32_t old63) {
  return (uint32_t)__builtin_amdgcn_update_dpp((int)old63, (int)src, 0x130, 0xF, 0xF, false);
}

// offset of diagonal d; lo(d)=max(1,d-512)
__device__ __forceinline__ int offd(int d) {
  return (d <= 513) ? (((d - 2) * (d - 1)) >> 1)
                    : (NCELL - (((1025 - d) * (1026 - d)) >> 1));
}
__device__ __forceinline__ int dbase(int d) {
  const int lo = (d > 513) ? d - 512 : 1;
  return offd(d) - lo;
}

// forward softmax-LSE cell (base-2 domain)
__device__ __forceinline__ void fcell(float& nv, uint32_t& pk, float dg, float up0,
                                      float lf0, float th, float A2) {
  float up = up0 + A2, lf = lf0 + A2;
  float mx = fmaxf(fmaxf(dg, up), lf);
  float ed = exp2f_(dg - mx), eu = exp2f_(up - mx), el = exp2f_(lf - mx);
  float s = ed + eu + el;
  nv = th + mx + log2f_(s);
  float rs = __builtin_amdgcn_rcpf(s);
  pk = pknorm16(ed * rs, eu * rs);
}

// ---------------------------------------------------------------------------
// K1: T[22][512] = W_embed @ W_proj + b_proj
// ---------------------------------------------------------------------------
__global__ void k_T(const float* __restrict__ We, const float* __restrict__ Wp,
                    const float* __restrict__ bp, float* __restrict__ T) {
  int a = blockIdx.x, c = threadIdx.x;
  __shared__ float e[512];
  e[c] = We[a * 512 + c];
  __syncthreads();
  float acc = bp[c];
#pragma unroll 8
  for (int k = 0; k < 512; ++k) acc = fmaf(e[k], Wp[k * 512 + c], acc);
  T[a * 512 + c] = acc;
}

// ---------------------------------------------------------------------------
// K2: G2[a][a2] (stride 37 for LDS bank spread) = (T T^T)/ln2 ; u,v gap LUTs
// ---------------------------------------------------------------------------
__global__ void k_G(const float* __restrict__ T, const float* __restrict__ Wg,
                    float* __restrict__ G, float* __restrict__ u, float* __restrict__ v) {
  __shared__ float Ts[22 * 516];
  for (int k = threadIdx.x; k < 22 * 512; k += 512) {
    int a = k >> 9, c = k & 511;
    Ts[a * 516 + c] = T[k];
  }
  __syncthreads();
  for (int idx = threadIdx.x; idx < 528; idx += 512) {
    float s = 0.f;
    if (idx < 484) {
      int a = idx / 22, a2 = idx - 22 * a;
      const float* pa = &Ts[a * 516];
      const float* pb = &Ts[a2 * 516];
      for (int c = 0; c < 512; ++c) s = fmaf(pa[c], pb[c], s);
      G[a * 37 + a2] = s * INVLN2;  // padded row stride 37
    } else if (idx < 506) {
      int a = idx - 484;
      const float* pa = &Ts[a * 516];
      for (int c = 0; c < 512; ++c) s = fmaf(pa[c], Wg[c], s);
      u[a] = s;
    } else {
      int a = idx - 506;
      const float* pa = &Ts[a * 516];
      for (int c = 0; c < 512; ++c) s = fmaf(pa[c], Wg[512 + c], s);
      v[a] = s;
    }
  }
}

// ---------------------------------------------------------------------------
// K3: A2[b]
// ---------------------------------------------------------------------------
__global__ void k_A(const int* __restrict__ x, const int* __restrict__ y,
                    const float* __restrict__ u, const float* __restrict__ v,
                    const float* __restrict__ bg, float* __restrict__ A) {
  int b = blockIdx.x, t = threadIdx.x;
  const int* xb = x + b * 512;
  const int* yb = y + b * 512;
  float s = u[xb[t]] + u[xb[t + 256]] + v[yb[t]] + v[yb[t + 256]];
  for (int o = 32; o > 0; o >>= 1) s += __shfl_down(s, o, 64);
  __shared__ float w[4];
  if ((t & 63) == 0) w[t >> 6] = s;
  __syncthreads();
  if (t == 0) A[b] = ((w[0] + w[1] + w[2] + w[3]) * (1.0f / 512.0f) + bg[0]) * INVLN2;
}

// ---------------------------------------------------------------------------
// K4: skewed 8-wave pipeline DP, KD=32 diagonals per barrier interval.
//     512 threads, 1 row/lane (r=64w+lane+1). mod-128 rings (double-write).
//     ys values for next interval prefetched to registers (no dep-gather stall).
// ---------------------------------------------------------------------------
__global__ __launch_bounds__(512) void k_nw(const int* __restrict__ x, const int* __restrict__ y,
                                            const float* __restrict__ G,
                                            const float* __restrict__ Aarr,
                                            uint32_t* __restrict__ po,
                                            float* __restrict__ ews) {
  const int tid = threadIdx.x;
  const int w = __builtin_amdgcn_readfirstlane(tid) >> 6;  // wave id, forced SGPR
  const int lane = tid & 63;
  __shared__ float Gl[814];        // 22 x 37
  __shared__ int ysPad[960];       // zeros [0,320), ys at [320,832), zeros [832,960)
  __shared__ float Vring[8][256];      // mod-128 double-write; Vring[w] read by wave w (fwd)
  __shared__ float Ering[8][256];      // Ering[w] read by wave w (bwd); written by w+1
  __shared__ uint32_t Pring[8][256];   // same indexing as Ering

  const int b = blockIdx.x;
  const int* xbp = x + b * 512;
  const int* ybp = y + b * 512;
  if (tid < 320) ysPad[tid] = 0;
  if (tid >= 384) ysPad[tid + 448] = 0;  // covers [832, 960)
  ysPad[320 + tid] = ybp[tid];
  for (int k = tid; k < 814; k += 512) Gl[k] = G[k];
  for (int k = tid; k < 2048; k += 512) {
    ((float*)Vring)[k] = NEGF;
    ((float*)Ering)[k] = 0.0f;
    ((uint32_t*)Pring)[k] = 0u;
  }
  const float A2 = Aarr[b];
  const int r = 64 * w + lane + 1;
  const int xr = xbp[r - 1] * 37;
  const bool lane0 = (lane == 0), lane63 = (lane == 63);
  const bool wgt0 = (w > 0), wlt7 = (w < 7);
  const bool rless = (r < 512);
  po += (size_t)b * NCELL;
  ews += (size_t)b * NCELL;
  __syncthreads();

  // ================= forward =================
  const int ivLoF = 2 * w;
  const int ivHiF = (3 * w + 17 < NIV - 1) ? 3 * w + 17 : NIV - 1;
  const int dnP0 = 2 + 32 * w;  // dn0 at ivLoF

#define DECLTH(m) float th##m;
  REP32(DECLTH)
#define DECLYA(m) int ya##m;
  REP32(DECLYA)
#define PROTH(m) { const int ix = (dnP0 + (m)) + 319 - r; th##m = Gl[xr + ysPad[ix]]; }
  REP32(PROTH)

  float va = NEGF, rupP = NEGF;
#pragma unroll 1
  for (int iv = 0; iv < NIV; ++iv) {
    if (iv >= ivLoF && iv <= ivHiF) {
      const int dn0 = 2 - 32 * w + 32 * iv;  // scalar
      // batch-load next interval's ys values into registers (stride-1, conflict-free)
      const int iya = dn0 + 351 - r;  // (dn0+32) - 1 - r + 320
#define LYA(m) ya##m = ysPad[iya + (m)];
      REP32(LYA)
      // ring prefetch (broadcast reads)
      const float* VrB = &Vring[w][(dn0 - 1) & 127];
#define DECLRV(k) float rv##k = VrB[(k) - 1];
      LIST1_32(DECLRV)

#define FSTEP(m, k) { \
    const int dn = dn0 + (m); \
    float rdg = rupP; \
    if ((m) == 0 && w == 0 && iv == 0) rdg = lane0 ? 0.0f : rdg; /* V[0,0]=0 corner */ \
    const float rup = dpp_shr1_f(va, rv##k); \
    float nv; uint32_t pk; \
    fcell(nv, pk, rdg, rup, va, th##m, A2); \
    const bool vv = (unsigned)(dn - r - 1) < 512u; \
    nv = vv ? nv : NEGF; \
    if (vv) po[dbase(dn) + r] = pk; \
    if (wlt7 && lane63) { const int sl = dn & 127; Vring[w + 1][sl] = nv; Vring[w + 1][sl + 128] = nv; } \
    th##m = Gl[xr + ya##m]; /* refill for next interval, reg-ready address */ \
    va = nv; rupP = rup; \
  }
      FSTEP(0, 1)  FSTEP(1, 2)  FSTEP(2, 3)  FSTEP(3, 4)  FSTEP(4, 5)  FSTEP(5, 6)  FSTEP(6, 7)  FSTEP(7, 8)
      FSTEP(8, 9)  FSTEP(9, 10) FSTEP(10, 11) FSTEP(11, 12) FSTEP(12, 13) FSTEP(13, 14) FSTEP(14, 15) FSTEP(15, 16)
      FSTEP(16, 17) FSTEP(17, 18) FSTEP(18, 19) FSTEP(19, 20) FSTEP(20, 21) FSTEP(21, 22) FSTEP(22, 23) FSTEP(23, 24)
      FSTEP(24, 25) FSTEP(25, 26) FSTEP(26, 27) FSTEP(27, 28) FSTEP(28, 29) FSTEP(29, 30) FSTEP(30, 31) FSTEP(31, 32)
    }
    BAR();
  }

  // ================= transition: drain p stores once =================
  asm volatile("s_waitcnt vmcnt(0)" ::: "memory");
  __threadfence_block();
  __syncthreads();

  // ================= backward =================
  const float inv16 = 1.0f / 65535.0f;
  const bool w7 = (w == 7);
  const int ivLoB = 14 - 2 * w;
  const int ivHiB = 38 - 3 * w;
  float ea = (w7 && lane63) ? 1.0f : 0.0f;
  float reaP = 0.0f;
  uint32_t rqP = 0u;
  if (w7 && lane63) ews[NCELL - 1] = 1.0f;  // E(512,512) seed (diag 1024)

#define DECLQ(k) uint32_t q##k, qn##k;
  REP33(DECLQ)
  {
    const int t0p = 799 + 32 * w;  // t0 at ivLoB
#define QLD0(k) q##k = po[dbase(t0p + 2 - (k)) + r];
    REP33(QLD0)
  }

#pragma unroll 1
  for (int iv = 0; iv < NIV; ++iv) {
    if (iv >= ivLoB && iv <= ivHiB) {
      const int t0 = 1247 - 32 * w - 32 * iv;  // scalar
      const float* ErB = &Ering[w][(t0 - 30) & 127];
      const uint32_t* PrB = &Pring[w][(t0 - 30) & 127];
#define DECLRE(k) float rE##k = ErB[32 - (k)]; uint32_t rP##k = PrB[32 - (k)];
      LIST1_32(DECLRE)
      // issue next-interval p loads (stay in flight across BAR)
      if (iv < ivHiB) {
        const int t0n = t0 - 32;
#define QLDN(k) qn##k = po[dbase(t0n + 2 - (k)) + r];
        REP33(QLDN)
      }

#define BSTEP(m, k) { \
    const int t = t0 - (m); \
    const float reb = reaP; \
    const float rea = dpp_shl1_f(ea, rE##k); \
    const uint32_t rq2 = rqP; \
    const uint32_t rq1 = dpp_shl1_u(q##k, rP##k); \
    const bool vd = (unsigned)(t - r - 1) < 512u; \
    const bool rt = (unsigned)(t - r) < 512u; \
    const float pd = (float)(rq2 & 0xffffu) * inv16; \
    const float pu = (float)(rq1 >> 16) * inv16; \
    const float pl = 1.0f - (float)(q##k & 0xffffu) * inv16 - (float)(q##k >> 16) * inv16; \
    float n = (rless ? rea * pu : 0.0f) + ((rless && rt) ? reb * pd : 0.0f) + (rt ? ea * pl : 0.0f); \
    n = vd ? n : 0.0f; \
    if (vd) ews[dbase(t) + r] = n; \
    if (wgt0 && lane0) { const int sl = t & 127; Ering[w - 1][sl] = n; Ering[w - 1][sl + 128] = n; } \
    ea = n; reaP = rea; rqP = rq1; \
  }
      BSTEP(0, 1)  BSTEP(1, 2)  BSTEP(2, 3)  BSTEP(3, 4)  BSTEP(4, 5)  BSTEP(5, 6)  BSTEP(6, 7)  BSTEP(7, 8)
      BSTEP(8, 9)  BSTEP(9, 10) BSTEP(10, 11) BSTEP(11, 12) BSTEP(12, 13) BSTEP(13, 14) BSTEP(14, 15) BSTEP(15, 16)
      BSTEP(16, 17) BSTEP(17, 18) BSTEP(18, 19) BSTEP(19, 20) BSTEP(20, 21) BSTEP(21, 22) BSTEP(22, 23) BSTEP(23, 24)
      BSTEP(24, 25) BSTEP(25, 26) BSTEP(26, 27) BSTEP(27, 28) BSTEP(28, 29) BSTEP(29, 30) BSTEP(30, 31) BSTEP(31, 32)

      // publish own p-packs for downstream reader (row = this wave's lane0 row)
      if (wgt0 && lane0) {
#define PWR(k) { const int sl = (t0 + 2 - (k)) & 127; Pring[w - 1][sl] = q##k; Pring[w - 1][sl + 128] = q##k; }
        REP33(PWR)
      }
      // roll pipelined q
      if (iv < ivHiB) {
#define QMV(k) q##k = qn##k;
        REP33(QMV)
      }
    }
    BAR();
  }
}

// ---------------------------------------------------------------------------
// K5: transpose diag-major E (ws) -> row-major out. 64x64 cell tiles.
// ---------------------------------------------------------------------------
__global__ __launch_bounds__(256) void k_tr(const float* __restrict__ ews, float* __restrict__ out) {
  const int blk = blockIdx.x;
  const int b = blk >> 6, ti = (blk >> 3) & 7, tj = blk & 7;
  const float* src = ews + (size_t)b * NCELL;
  float* dst = out + (size_t)b * NCELL;
  __shared__ float tile[64][68];
  const int i0 = ti * 64, j0 = tj * 64;
  const int t = threadIdx.x;
  const int sub = t >> 6, lane = t & 63;
  for (int k = sub; k < 127; k += 4) {
    const int d = i0 + j0 + 2 + k;
    const int ilo_t = max(i0 + 1, d - (j0 + 64));
    const int ihi_t = min(i0 + 64, d - (j0 + 1));
    const int i = ilo_t + lane;
    if (i <= ihi_t) {
      const int lo = (d > 513) ? d - 512 : 1;
      tile[i - 1 - i0][d - i - 1 - j0] = src[offd(d) - lo + i];
    }
  }
  __syncthreads();
  const int rr = t >> 2, q = (t & 3) * 16;
  float4* drow = (float4*)&dst[(size_t)(i0 + rr) * 512 + j0 + q];
  const float* srow = &tile[rr][q];
  drow[0] = *(const float4*)&srow[0];
  drow[1] = *(const float4*)&srow[4];
  drow[2] = *(const float4*)&srow[8];
  drow[3] = *(const float4*)&srow[12];
}

// ---------------------------------------------------------------------------
extern "C" void kernel_launch(void* const* d_in, const int* in_sizes, int n_in,
                              void* d_out, int out_size, void* d_ws, size_t ws_size,
                              hipStream_t stream) {
  const int* x = (const int*)d_in[0];
  const int* y = (const int*)d_in[1];
  const float* We = (const float*)d_in[2];
  const float* Wp = (const float*)d_in[3];
  const float* bp = (const float*)d_in[4];
  const float* Wg = (const float*)d_in[5];
  const float* bg = (const float*)d_in[6];
  float* out = (float*)d_out;

  float* ws = (float*)d_ws;
  float* T = ws;              // 22*512 floats
  float* G = ws + 11264;      // 814 (22x37 padded)
  float* u = G + 814;         // 22
  float* v = u + 22;          // 22
  float* A = v + 22;          // 16
  float* ews = (float*)((char*)d_ws + (1 << 20));  // 16 MiB diag-major E

  k_T<<<22, 512, 0, stream>>>(We, Wp, bp, T);
  k_G<<<1, 512, 0, stream>>>(T, Wg, G, u, v);
  k_A<<<16, 256, 0, stream>>>(x, y, u, v, bg, A);
  k_nw<<<16, 512, 0, stream>>>(x, y, G, A, (uint32_t*)d_out, ews);
  k_tr<<<16 * 64, 256, 0, stream>>>(ews, out);
}